// Round 10
// baseline (294.417 us; speedup 1.0000x reference)
//
#include <hip/hip_runtime.h>
#include <hip/hip_bf16.h>
#include <math.h>

// ---------------- fp16 helpers ----------------
// Types derived from the builtins themselves (__fp16-based on gfx950) to avoid
// _Float16/__fp16 ext-vector init mismatches (R8 compile failure).

using pkh2 = decltype(__builtin_amdgcn_cvt_pkrtz(0.f, 0.f));   // 2 x __fp16
typedef __fp16 half8v __attribute__((ext_vector_type(8)));     // MFMA A/B frag
typedef __attribute__((ext_vector_type(4))) float f32x4;       // MFMA accumulator

__device__ __forceinline__ unsigned cvt2h(float a, float b) {  // 2xf32 -> packed f16
    pkh2 r = __builtin_amdgcn_cvt_pkrtz(a, b);
    return __builtin_bit_cast(unsigned, r);
}
__device__ __forceinline__ unsigned short f2h(float f) {
    return __builtin_bit_cast(unsigned short, (_Float16)f);
}

// acc += wpair . hpair  (both packed f16 pairs), f32 accumulate
__device__ __forceinline__ float fdot2b(unsigned wp, unsigned hp, float c) {
#if __has_builtin(__builtin_amdgcn_fdot2)
    return __builtin_amdgcn_fdot2(__builtin_bit_cast(pkh2, wp),
                                  __builtin_bit_cast(pkh2, hp), c, false);
#else
    pkh2 w = __builtin_bit_cast(pkh2, wp), h = __builtin_bit_cast(pkh2, hp);
    return fmaf((float)w[0], (float)h[0], fmaf((float)w[1], (float)h[1], c));
#endif
}

// ================= CSR build: bucket-binned counting sort =================
// Items 0..E-1 are edges (src=ei[i], dst=ei[E+i]); items E..E+N-1 are self loops.
// Bucket b = dst >> 8. All per-node atomics in LDS; csr writes confined to one
// bucket's window per block (lines fully populated before writeback).

__global__ void init_k(int* __restrict__ bucketCnt, float* __restrict__ g) {
    int i = threadIdx.x;
    if (i < 512) bucketCnt[i] = 0;
    if (i < 66)  g[i] = 0.f;
}

__global__ void bucket_hist_k(const int* __restrict__ ei, int* __restrict__ bucketCnt,
                              int E, int N, int NB) {
    __shared__ int cnt[512];
    for (int t = threadIdx.x; t < 512; t += blockDim.x) cnt[t] = 0;
    __syncthreads();
    const int ITEMS = E + N;
    for (int i = blockIdx.x * blockDim.x + threadIdx.x; i < ITEMS;
         i += gridDim.x * blockDim.x) {
        int d = (i < E) ? ei[E + i] : (i - E);
        atomicAdd(&cnt[d >> 8], 1);
    }
    __syncthreads();
    for (int t = threadIdx.x; t < NB; t += blockDim.x)
        if (cnt[t]) atomicAdd(&bucketCnt[t], cnt[t]);
}

__global__ void bucket_scan_k(const int* __restrict__ bucketCnt,
                              int* __restrict__ bucketOff,
                              int* __restrict__ bucketFill, int NB) {
    __shared__ int ls[512];
    int t = threadIdx.x;
    int v = (t < NB) ? bucketCnt[t] : 0;
    ls[t] = v;
    __syncthreads();
    for (int off = 1; off < 512; off <<= 1) {
        int a = (t >= off) ? ls[t - off] : 0;
        __syncthreads();
        ls[t] += a;
        __syncthreads();
    }
    if (t < NB) { int e = ls[t] - v; bucketOff[t] = e; bucketFill[t] = e; }
}

__global__ __launch_bounds__(256) void bin_scatter_k(const int* __restrict__ ei,
                                                     int* __restrict__ bucketFill,
                                                     int2* __restrict__ binned,
                                                     int E, int N) {
    __shared__ int cnt[512];
    __shared__ int base[512];
    const int ITEMS = E + N;
    const int t = threadIdx.x;
    const int chunk0 = blockIdx.x * 4096;
    for (int b = t; b < 512; b += 256) cnt[b] = 0;
    __syncthreads();
    int s[16], d[16], r[16];
#pragma unroll
    for (int j = 0; j < 16; j++) {
        int i = chunk0 + j * 256 + t;
        if (i < ITEMS) {
            if (i < E) { s[j] = ei[i]; d[j] = ei[E + i]; }
            else       { s[j] = d[j] = i - E; }
            r[j] = atomicAdd(&cnt[d[j] >> 8], 1);
        } else d[j] = -1;
    }
    __syncthreads();
    for (int b = t; b < 512; b += 256) {
        int c = cnt[b];
        base[b] = c ? atomicAdd(&bucketFill[b], c) : 0;
    }
    __syncthreads();
#pragma unroll
    for (int j = 0; j < 16; j++)
        if (d[j] >= 0) binned[base[d[j] >> 8] + r[j]] = make_int2(s[j], d[j]);
}

// fused per-bucket node histogram + LDS scan -> offs written directly
__global__ void node_offs_k(const int2* __restrict__ binned,
                            const int* __restrict__ bucketOff,
                            const int* __restrict__ bucketCnt,
                            int* __restrict__ offs, int N, int ITEMS) {
    __shared__ int cnt[256];
    __shared__ int ls[256];
    const int b = blockIdx.x;
    const int t = threadIdx.x;
    cnt[t] = 0;
    __syncthreads();
    const int beg = bucketOff[b], c = bucketCnt[b];
    for (int i = t; i < c; i += 256)
        atomicAdd(&cnt[binned[beg + i].y & 255], 1);
    __syncthreads();
    int v = cnt[t];
    ls[t] = v;
    __syncthreads();
    for (int off = 1; off < 256; off <<= 1) {
        int a = (t >= off) ? ls[t - off] : 0;
        __syncthreads();
        ls[t] += a;
        __syncthreads();
    }
    int node = b * 256 + t;
    if (node < N) offs[node] = beg + ls[t] - v;
    if (node == N - 1) offs[N] = ITEMS;
}

__global__ void csr_scatter_k(const int2* __restrict__ binned,
                              const int* __restrict__ bucketOff,
                              const int* __restrict__ bucketCnt,
                              const int* __restrict__ offs, int* __restrict__ csr) {
    __shared__ int fill[256];
    const int b = blockIdx.x;
    fill[threadIdx.x] = 0;
    __syncthreads();
    const int beg = bucketOff[b], c = bucketCnt[b];
    for (int i = threadIdx.x; i < c; i += 256) {
        int2 sd = binned[beg + i];
        int r = atomicAdd(&fill[sd.y & 255], 1);
        csr[offs[sd.y] + r] = sd.x;
    }
}

// ======= MFMA GEMM: Y[M,NCOL](f16) = X[M,128] @ W[128,NCOL] + fused alpha =======
// v_mfma_f32_16x16x32_f16, fragment layouts (dtype-independent, m89/m121):
//   A: lane l holds A[l&15][(l>>4)*8 + j];  B: lane l holds B[(l>>4)*8 + j][l&15]
//   D: lane l, reg j -> row (l>>4)*4+j, col l&15
// A/B staged to LDS in fragment-contiguous order -> lane-contiguous ds_read_b128.
// (cross-type LDS accesses here are safe: separated by __syncthreads, a full fence)

template<int NCOL, bool XF16>
__global__ __launch_bounds__(256) void gemm_alpha_mfma(
        const void* __restrict__ Xv, const float* __restrict__ W,
        const float* __restrict__ asrc, const float* __restrict__ adst,
        unsigned short* __restrict__ Y, float* __restrict__ As,
        float* __restrict__ Ad, int M) {
    constexpr int NT = NCOL / 16;            // 8 (layer1) or 4 (layer2)
    __shared__ alignas(16) short alds[4 * 4 * 64 * 8];      // [w][ks][lane][8]
    __shared__ alignas(16) short blds[NT * 4 * 64 * 8];     // [nt][ks][lane][8]

    const int t    = threadIdx.x;
    const int w    = t >> 6, lane = t & 63;
    const int row0 = blockIdx.x * 64;

    // ---- stage A tile (64 x 128) as f16 fragments ----
    if constexpr (!XF16) {
        const float* X = (const float*)Xv;
#pragma unroll
        for (int i = 0; i < 8; i++) {
            int flat = (i * 256 + t) * 4;
            int r = flat >> 7, k0 = flat & 127;
            int gr = row0 + r;
            float4 v = make_float4(0.f, 0.f, 0.f, 0.f);
            if (gr < M) v = *(const float4*)&X[(size_t)gr * 128 + k0];
            uint2 u = make_uint2(cvt2h(v.x, v.y), cvt2h(v.z, v.w));
            int frag = ((r >> 4) * 4 + (k0 >> 5)) * 64 + ((((k0 & 31) >> 3) << 4) | (r & 15));
            *(uint2*)&alds[frag * 8 + (k0 & 7)] = u;
        }
    } else {
        const unsigned short* X = (const unsigned short*)Xv;
#pragma unroll
        for (int i = 0; i < 4; i++) {
            int flat = (i * 256 + t) * 8;
            int r = flat >> 7, k0 = flat & 127;
            int gr = row0 + r;
            uint4 v = make_uint4(0u, 0u, 0u, 0u);
            if (gr < M) v = *(const uint4*)&X[(size_t)gr * 128 + k0];
            int frag = ((r >> 4) * 4 + (k0 >> 5)) * 64 + ((((k0 & 31) >> 3) << 4) | (r & 15));
            *(uint4*)&alds[frag * 8] = v;   // k0 % 8 == 0
        }
    }

    // ---- stage B (W: 128 x NCOL fp32) as f16 fragments ----
    {
        constexpr int KQ = 256 / NCOL;       // 2 or 4 k-quads covered per pass
        constexpr int BITER = 32 / KQ;       // 16 or 8 iterations
        int c = t % NCOL, kq = t / NCOL;
        int nt = c >> 4, n = c & 15;
#pragma unroll
        for (int i = 0; i < BITER; i++) {
            int k0 = (i * KQ + kq) * 4;
            uint2 u = make_uint2(
                cvt2h(W[(size_t)(k0 + 0) * NCOL + c], W[(size_t)(k0 + 1) * NCOL + c]),
                cvt2h(W[(size_t)(k0 + 2) * NCOL + c], W[(size_t)(k0 + 3) * NCOL + c]));
            int frag = (nt * 4 + (k0 >> 5)) * 64 + ((((k0 & 31) >> 3) << 4) | n);
            *(uint2*)&blds[frag * 8 + (k0 & 7)] = u;
        }
    }
    __syncthreads();

    // ---- MFMA: 16 rows x NCOL per wave ----
    f32x4 acc[NT];
#pragma unroll
    for (int nt = 0; nt < NT; nt++) acc[nt] = (f32x4){0.f, 0.f, 0.f, 0.f};
#pragma unroll
    for (int ks = 0; ks < 4; ks++) {
        half8v a = *(half8v*)&alds[((w * 4 + ks) * 64 + lane) * 8];
#pragma unroll
        for (int nt = 0; nt < NT; nt++) {
            half8v b = *(half8v*)&blds[((nt * 4 + ks) * 64 + lane) * 8];
            acc[nt] = __builtin_amdgcn_mfma_f32_16x16x32_f16(a, b, acc[nt], 0, 0, 0);
        }
    }

    // ---- epilogue: f16 store + alpha dots ----
    const int g = lane >> 4, col = lane & 15;
    float ps[4][4] = {}, pd[4][4] = {};      // [reg j][head]
#pragma unroll
    for (int nt = 0; nt < NT; nt++) {
        float av = asrc[nt * 16 + col];
        float dv = adst[nt * 16 + col];
        int h = (NCOL == 128) ? (nt >> 1) : nt;
#pragma unroll
        for (int j = 0; j < 4; j++) {
            float v = acc[nt][j];
            ps[j][h] = fmaf(v, av, ps[j][h]);
            pd[j][h] = fmaf(v, dv, pd[j][h]);
            int gr = row0 + w * 16 + 4 * g + j;
            if (gr < M) Y[(size_t)gr * NCOL + nt * 16 + col] = f2h(v);
        }
    }
#pragma unroll
    for (int m = 1; m < 16; m <<= 1) {
#pragma unroll
        for (int j = 0; j < 4; j++)
#pragma unroll
            for (int h = 0; h < 4; h++) {
                ps[j][h] += __shfl_xor(ps[j][h], m);
                pd[j][h] += __shfl_xor(pd[j][h], m);
            }
    }
    if (col == 0) {
#pragma unroll
        for (int j = 0; j < 4; j++) {
            int gr = row0 + w * 16 + 4 * g + j;
            if (gr < M) {
#pragma unroll
                for (int h = 0; h < 4; h++) {
                    As[gr * 4 + h] = ps[j][h];
                    Ad[gr * 4 + h] = pd[j][h];
                }
            }
        }
    }
}

// ------- aggregation: one wave per dst node ----------------------------------
// out[i] = ( sum_{e:dst=i} exp(leaky(As[src]+Ad[i])) * h[src] ) / sum exp(...)
// (segment-max dropped: softmax ratio invariant; e ~ N(0,0.7) -> f16-safe)
// Per 64-edge block, each lane precomputes edge `lane`'s weights for ALL 4
// heads into a per-wave LDS table [head][edge] (f16). Inner loop: weight pair
// read back as TWO ushort loads (matching type -> no TBAA hazard; compiler may
// legally fuse) + compiler fence after the writes -- the R9 bug was a u32 read
// of the u16 table with no barrier, which TBAA may hoist above the writes.

template<bool RELU>
__global__ void agg128_k(const unsigned short* __restrict__ Hb,
                         const float* __restrict__ As, const float* __restrict__ Ad,
                         const int* __restrict__ offs, const int* __restrict__ csr,
                         const float* __restrict__ bias,
                         unsigned short* __restrict__ Outb, int n) {
    __shared__ unsigned short wlds[4][4 * 64];   // [wave][head*64 + edge]
    int wid  = (blockIdx.x * blockDim.x + threadIdx.x) >> 6;
    int lane = threadIdx.x & 63;
    if (wid >= n) return;
    const int wv = (threadIdx.x >> 6) & 3;
    const int g = lane >> 4;          // edge-slot group (0..3)
    const int q = lane & 15;          // channel octet
    const int head = q >> 2;
    const int beg = offs[wid], end = offs[wid + 1];
    const float4 ad4 = *(const float4*)&Ad[wid * 4];
    float acc[8];
#pragma unroll
    for (int k = 0; k < 8; k++) acc[k] = 0.f;
    float4 sw4 = make_float4(0.f, 0.f, 0.f, 0.f);

    for (int cb = beg; cb < end; cb += 64) {
        const int nc = min(64, end - cb);
        const int sreg = csr[cb + min(lane, nc - 1)];        // 1 coalesced load
        // --- precompute: weights for edge `lane`, all 4 heads ---
        {
            const float4 as4 = *(const float4*)&As[(size_t)sreg * 4];
            float w0 = 0.f, w1 = 0.f, w2 = 0.f, w3 = 0.f;
            if (lane < nc) {
                float e0 = as4.x + ad4.x; e0 = e0 > 0.f ? e0 : 0.2f * e0;
                float e1 = as4.y + ad4.y; e1 = e1 > 0.f ? e1 : 0.2f * e1;
                float e2 = as4.z + ad4.z; e2 = e2 > 0.f ? e2 : 0.2f * e2;
                float e3 = as4.w + ad4.w; e3 = e3 > 0.f ? e3 : 0.2f * e3;
                w0 = __expf(e0); w1 = __expf(e1); w2 = __expf(e2); w3 = __expf(e3);
            }
            sw4.x += w0; sw4.y += w1; sw4.z += w2; sw4.w += w3;
            wlds[wv][0 * 64 + lane] = f2h(w0);
            wlds[wv][1 * 64 + lane] = f2h(w1);
            wlds[wv][2 * 64 + lane] = f2h(w2);
            wlds[wv][3 * 64 + lane] = f2h(w3);
        }
        asm volatile("" ::: "memory");   // order table writes before reads (TBAA fence)
        const int ncr = (nc + 7) & ~7;
        for (int j = 0; j < ncr; j += 8) {
            const int e0 = j + 2 * g;                        // pair (e0, e0+1)
            const int s0 = __shfl(sreg, e0);
            const int s1 = __shfl(sreg, e0 + 1);
            const unsigned wlo = wlds[wv][head * 64 + e0];
            const unsigned whi = wlds[wv][head * 64 + e0 + 1];
            const unsigned wp = wlo | (whi << 16);
            const uint4 h0 = *(const uint4*)&Hb[(size_t)s0 * 128 + q * 8];
            const uint4 h1 = *(const uint4*)&Hb[(size_t)s1 * 128 + q * 8];
#pragma unroll
            for (int k = 0; k < 4; k++) {
                unsigned d0 = (&h0.x)[k], d1 = (&h1.x)[k];
                acc[2 * k]     = fdot2b(wp, __builtin_amdgcn_perm(d1, d0, 0x05040100u), acc[2 * k]);
                acc[2 * k + 1] = fdot2b(wp, __builtin_amdgcn_perm(d1, d0, 0x07060302u), acc[2 * k + 1]);
            }
        }
    }

#pragma unroll
    for (int m = 1; m < 64; m <<= 1) {
        sw4.x += __shfl_xor(sw4.x, m); sw4.y += __shfl_xor(sw4.y, m);
        sw4.z += __shfl_xor(sw4.z, m); sw4.w += __shfl_xor(sw4.w, m);
    }
#pragma unroll
    for (int k = 0; k < 8; k++) {
        acc[k] += __shfl_xor(acc[k], 16);
        acc[k] += __shfl_xor(acc[k], 32);
    }
    if (g == 0) {
        float swh = head < 2 ? (head == 0 ? sw4.x : sw4.y)
                             : (head == 2 ? sw4.z : sw4.w);
        const float inv = 1.f / swh;
        float o[8];
#pragma unroll
        for (int k = 0; k < 8; k++) {
            float v = fmaf(acc[k], inv, bias[q * 8 + k]);
            if (RELU) v = fmaxf(v, 0.f);
            o[k] = v;
        }
        uint4 ov = make_uint4(cvt2h(o[0], o[1]), cvt2h(o[2], o[3]),
                              cvt2h(o[4], o[5]), cvt2h(o[6], o[7]));
        *(uint4*)&Outb[(size_t)wid * 128 + q * 8] = ov;
    }
}

__global__ void agg64_k(const unsigned short* __restrict__ Hb,
                        const float* __restrict__ As, const float* __restrict__ Ad,
                        const int* __restrict__ offs, const int* __restrict__ csr,
                        const float* __restrict__ bias,
                        float* __restrict__ Out, int n) {
    __shared__ unsigned short wlds[4][4 * 64];
    int wid  = (blockIdx.x * blockDim.x + threadIdx.x) >> 6;
    int lane = threadIdx.x & 63;
    if (wid >= n) return;
    const int wv = (threadIdx.x >> 6) & 3;
    const int g = lane >> 3;          // edge-slot group (0..7)
    const int q = lane & 7;           // channel octet
    const int head = q >> 1;
    const int beg = offs[wid], end = offs[wid + 1];
    const float4 ad4 = *(const float4*)&Ad[wid * 4];
    float acc[8];
#pragma unroll
    for (int k = 0; k < 8; k++) acc[k] = 0.f;
    float4 sw4 = make_float4(0.f, 0.f, 0.f, 0.f);

    for (int cb = beg; cb < end; cb += 64) {
        const int nc = min(64, end - cb);
        const int sreg = csr[cb + min(lane, nc - 1)];
        {
            const float4 as4 = *(const float4*)&As[(size_t)sreg * 4];
            float w0 = 0.f, w1 = 0.f, w2 = 0.f, w3 = 0.f;
            if (lane < nc) {
                float e0 = as4.x + ad4.x; e0 = e0 > 0.f ? e0 : 0.2f * e0;
                float e1 = as4.y + ad4.y; e1 = e1 > 0.f ? e1 : 0.2f * e1;
                float e2 = as4.z + ad4.z; e2 = e2 > 0.f ? e2 : 0.2f * e2;
                float e3 = as4.w + ad4.w; e3 = e3 > 0.f ? e3 : 0.2f * e3;
                w0 = __expf(e0); w1 = __expf(e1); w2 = __expf(e2); w3 = __expf(e3);
            }
            sw4.x += w0; sw4.y += w1; sw4.z += w2; sw4.w += w3;
            wlds[wv][0 * 64 + lane] = f2h(w0);
            wlds[wv][1 * 64 + lane] = f2h(w1);
            wlds[wv][2 * 64 + lane] = f2h(w2);
            wlds[wv][3 * 64 + lane] = f2h(w3);
        }
        asm volatile("" ::: "memory");   // order table writes before reads (TBAA fence)
        const int ncr = (nc + 15) & ~15;
        for (int j = 0; j < ncr; j += 16) {
            const int e0 = j + 2 * g;
            const int s0 = __shfl(sreg, e0);
            const int s1 = __shfl(sreg, e0 + 1);
            const unsigned wlo = wlds[wv][head * 64 + e0];
            const unsigned whi = wlds[wv][head * 64 + e0 + 1];
            const unsigned wp = wlo | (whi << 16);
            const uint4 h0 = *(const uint4*)&Hb[(size_t)s0 * 64 + q * 8];
            const uint4 h1 = *(const uint4*)&Hb[(size_t)s1 * 64 + q * 8];
#pragma unroll
            for (int k = 0; k < 4; k++) {
                unsigned d0 = (&h0.x)[k], d1 = (&h1.x)[k];
                acc[2 * k]     = fdot2b(wp, __builtin_amdgcn_perm(d1, d0, 0x05040100u), acc[2 * k]);
                acc[2 * k + 1] = fdot2b(wp, __builtin_amdgcn_perm(d1, d0, 0x07060302u), acc[2 * k + 1]);
            }
        }
    }

#pragma unroll
    for (int m = 1; m < 64; m <<= 1) {
        sw4.x += __shfl_xor(sw4.x, m); sw4.y += __shfl_xor(sw4.y, m);
        sw4.z += __shfl_xor(sw4.z, m); sw4.w += __shfl_xor(sw4.w, m);
    }
#pragma unroll
    for (int k = 0; k < 8; k++) {
        acc[k] += __shfl_xor(acc[k], 8);
        acc[k] += __shfl_xor(acc[k], 16);
        acc[k] += __shfl_xor(acc[k], 32);
    }
    if (g == 0) {
        float swh = head < 2 ? (head == 0 ? sw4.x : sw4.y)
                             : (head == 2 ? sw4.z : sw4.w);
        const float inv = 1.f / swh;
        float4 o0, o1;
        o0.x = fmaf(acc[0], inv, bias[q * 8 + 0]);
        o0.y = fmaf(acc[1], inv, bias[q * 8 + 1]);
        o0.z = fmaf(acc[2], inv, bias[q * 8 + 2]);
        o0.w = fmaf(acc[3], inv, bias[q * 8 + 3]);
        o1.x = fmaf(acc[4], inv, bias[q * 8 + 4]);
        o1.y = fmaf(acc[5], inv, bias[q * 8 + 5]);
        o1.z = fmaf(acc[6], inv, bias[q * 8 + 6]);
        o1.w = fmaf(acc[7], inv, bias[q * 8 + 7]);
        *(float4*)&Out[(size_t)wid * 64 + q * 8]     = o0;
        *(float4*)&Out[(size_t)wid * 64 + q * 8 + 4] = o1;
    }
}

// ---------------- global add pool + FC ----------------

__global__ void pool_k(const float* __restrict__ h2, float* __restrict__ g, int n) {
    __shared__ float ls[256];
    int c   = threadIdx.x & 63;
    int rg  = (blockIdx.x * blockDim.x + threadIdx.x) >> 6;
    int nrg = (gridDim.x * blockDim.x) >> 6;
    float acc = 0.f;
    for (int r = rg; r < n; r += nrg) acc += h2[(size_t)r * 64 + c];
    ls[threadIdx.x] = acc;
    __syncthreads();
    if (threadIdx.x < 64) {
        float v = ls[threadIdx.x] + ls[threadIdx.x + 64] +
                  ls[threadIdx.x + 128] + ls[threadIdx.x + 192];
        atomicAdd(&g[c], v);
    }
}

__global__ void fc_k(const float* __restrict__ g, const float* __restrict__ w,
                     const float* __restrict__ b, float* __restrict__ out) {
    int j = threadIdx.x;
    if (j < 2) {
        float acc = b[j];
        for (int c = 0; c < 64; c++) acc = fmaf(g[c], w[c * 2 + j], acc);
        out[j] = acc;
    }
}

// ---------------- launch ----------------

static inline size_t align256(size_t x) { return (x + 255) & ~(size_t)255; }

extern "C" void kernel_launch(void* const* d_in, const int* in_sizes, int n_in,
                              void* d_out, int out_size, void* d_ws, size_t ws_size,
                              hipStream_t stream) {
    const float* x     = (const float*)d_in[0];
    const int*   ei    = (const int*)  d_in[1];
    const float* W1    = (const float*)d_in[2];
    const float* asrc1 = (const float*)d_in[3];
    const float* adst1 = (const float*)d_in[4];
    const float* b1    = (const float*)d_in[5];
    const float* W2    = (const float*)d_in[6];
    const float* asrc2 = (const float*)d_in[7];
    const float* adst2 = (const float*)d_in[8];
    const float* b2    = (const float*)d_in[9];
    const float* fcw   = (const float*)d_in[10];
    const float* fcb   = (const float*)d_in[11];
    float* out = (float*)d_out;

    const int N = in_sizes[0] / 128;
    const int E = in_sizes[1] / 2;
    const int ITEMS = E + N;
    const int NB = (N + 255) >> 8;

    // workspace carve-up
    char* w = (char*)d_ws;
    size_t off = 0;
    int* offs  = (int*)(w + off); off = align256(off + (size_t)(N + 1) * 4);
    int* bCnt  = (int*)(w + off); off = align256(off + 512 * 4);
    int* bOff  = (int*)(w + off); off = align256(off + 512 * 4);
    int* bFill = (int*)(w + off); off = align256(off + 512 * 4);
    int* csr   = (int*)(w + off); off = align256(off + (size_t)ITEMS * 4);
    int2* binned = (int2*)(w + off); off = align256(off + (size_t)ITEMS * 8);
    float* As = (float*)(w + off); off = align256(off + (size_t)N * 4 * 4);
    float* Ad = (float*)(w + off); off = align256(off + (size_t)N * 4 * 4);
    float* g  = (float*)(w + off); off = align256(off + 66 * 4);
    unsigned short* bufH = (unsigned short*)(w + off); off = align256(off + (size_t)N * 128 * 2);
    unsigned short* bufO = (unsigned short*)(w + off); off = align256(off + (size_t)N * 128 * 4);
    float* out2 = (float*)bufO;   // layer-2 output aliases bufO (fp32, N x 64)

    // --- build CSR (by dst, self loops included) ---
    init_k<<<1, 512, 0, stream>>>(bCnt, g);
    bucket_hist_k<<<1024, 256, 0, stream>>>(ei, bCnt, E, N, NB);
    bucket_scan_k<<<1, 512, 0, stream>>>(bCnt, bOff, bFill, NB);
    bin_scatter_k<<<(ITEMS + 4095) / 4096, 256, 0, stream>>>(ei, bFill, binned, E, N);
    node_offs_k<<<NB, 256, 0, stream>>>(binned, bOff, bCnt, offs, N, ITEMS);
    csr_scatter_k<<<NB, 256, 0, stream>>>(binned, bOff, bCnt, offs, csr);

    // --- layer 1 ---
    gemm_alpha_mfma<128, false><<<(N + 63) / 64, 256, 0, stream>>>(
        x, W1, asrc1, adst1, bufH, As, Ad, N);
    agg128_k<true><<<(N * 64 + 255) / 256, 256, 0, stream>>>(
        bufH, As, Ad, offs, csr, b1, bufO, N);

    // --- layer 2 ---
    gemm_alpha_mfma<64, true><<<(N + 63) / 64, 256, 0, stream>>>(
        bufO, W2, asrc2, adst2, bufH, As, Ad, N);
    agg64_k<<<(N * 64 + 255) / 256, 256, 0, stream>>>(
        bufH, As, Ad, offs, csr, b2, out2, N);

    // --- pool + fc ---
    pool_k<<<256, 256, 0, stream>>>(out2, g, N);
    fc_k<<<1, 64, 0, stream>>>(g, fcw, fcb, out);
}

// Round 11
// 272.582 us; speedup vs baseline: 1.0801x; 1.0801x over previous
//
#include <hip/hip_runtime.h>
#include <hip/hip_bf16.h>
#include <math.h>

// ---------------- fp16 helpers ----------------
// Types derived from the builtins themselves (__fp16-based on gfx950) to avoid
// _Float16/__fp16 ext-vector init mismatches (R8 compile failure).

using pkh2 = decltype(__builtin_amdgcn_cvt_pkrtz(0.f, 0.f));   // 2 x __fp16
typedef __fp16 half8v __attribute__((ext_vector_type(8)));     // MFMA A/B frag
typedef __attribute__((ext_vector_type(4))) float f32x4;       // MFMA accumulator

__device__ __forceinline__ unsigned cvt2h(float a, float b) {  // 2xf32 -> packed f16
    pkh2 r = __builtin_amdgcn_cvt_pkrtz(a, b);
    return __builtin_bit_cast(unsigned, r);
}
__device__ __forceinline__ unsigned short f2h(float f) {
    return __builtin_bit_cast(unsigned short, (_Float16)f);
}

// acc += wpair . hpair  (both packed f16 pairs), f32 accumulate
__device__ __forceinline__ float fdot2b(unsigned wp, unsigned hp, float c) {
#if __has_builtin(__builtin_amdgcn_fdot2)
    return __builtin_amdgcn_fdot2(__builtin_bit_cast(pkh2, wp),
                                  __builtin_bit_cast(pkh2, hp), c, false);
#else
    pkh2 w = __builtin_bit_cast(pkh2, wp), h = __builtin_bit_cast(pkh2, hp);
    return fmaf((float)w[0], (float)h[0], fmaf((float)w[1], (float)h[1], c));
#endif
}

// ================= CSR build: bucket-binned counting sort =================
// Items 0..E-1 are edges (src=ei[i], dst=ei[E+i]); items E..E+N-1 are self loops.
// Bucket b = dst >> 8. All per-node atomics in LDS; csr writes confined to one
// bucket's window per block (lines fully populated before writeback).

__global__ void init_k(int* __restrict__ bucketCnt, float* __restrict__ g) {
    int i = threadIdx.x;
    if (i < 512) bucketCnt[i] = 0;
    if (i < 66)  g[i] = 0.f;
}

__global__ void bucket_hist_k(const int* __restrict__ ei, int* __restrict__ bucketCnt,
                              int E, int N, int NB) {
    __shared__ int cnt[512];
    for (int t = threadIdx.x; t < 512; t += blockDim.x) cnt[t] = 0;
    __syncthreads();
    const int ITEMS = E + N;
    for (int i = blockIdx.x * blockDim.x + threadIdx.x; i < ITEMS;
         i += gridDim.x * blockDim.x) {
        int d = (i < E) ? ei[E + i] : (i - E);
        atomicAdd(&cnt[d >> 8], 1);
    }
    __syncthreads();
    for (int t = threadIdx.x; t < NB; t += blockDim.x)
        if (cnt[t]) atomicAdd(&bucketCnt[t], cnt[t]);
}

__global__ void bucket_scan_k(const int* __restrict__ bucketCnt,
                              int* __restrict__ bucketOff,
                              int* __restrict__ bucketFill, int NB) {
    __shared__ int ls[512];
    int t = threadIdx.x;
    int v = (t < NB) ? bucketCnt[t] : 0;
    ls[t] = v;
    __syncthreads();
    for (int off = 1; off < 512; off <<= 1) {
        int a = (t >= off) ? ls[t - off] : 0;
        __syncthreads();
        ls[t] += a;
        __syncthreads();
    }
    if (t < NB) { int e = ls[t] - v; bucketOff[t] = e; bucketFill[t] = e; }
}

__global__ __launch_bounds__(256) void bin_scatter_k(const int* __restrict__ ei,
                                                     int* __restrict__ bucketFill,
                                                     int2* __restrict__ binned,
                                                     int E, int N) {
    __shared__ int cnt[512];
    __shared__ int base[512];
    const int ITEMS = E + N;
    const int t = threadIdx.x;
    const int chunk0 = blockIdx.x * 4096;
    for (int b = t; b < 512; b += 256) cnt[b] = 0;
    __syncthreads();
    int s[16], d[16], r[16];
#pragma unroll
    for (int j = 0; j < 16; j++) {
        int i = chunk0 + j * 256 + t;
        if (i < ITEMS) {
            if (i < E) { s[j] = ei[i]; d[j] = ei[E + i]; }
            else       { s[j] = d[j] = i - E; }
            r[j] = atomicAdd(&cnt[d[j] >> 8], 1);
        } else d[j] = -1;
    }
    __syncthreads();
    for (int b = t; b < 512; b += 256) {
        int c = cnt[b];
        base[b] = c ? atomicAdd(&bucketFill[b], c) : 0;
    }
    __syncthreads();
#pragma unroll
    for (int j = 0; j < 16; j++)
        if (d[j] >= 0) binned[base[d[j] >> 8] + r[j]] = make_int2(s[j], d[j]);
}

// fused per-bucket node histogram + LDS scan -> offs written directly
__global__ void node_offs_k(const int2* __restrict__ binned,
                            const int* __restrict__ bucketOff,
                            const int* __restrict__ bucketCnt,
                            int* __restrict__ offs, int N, int ITEMS) {
    __shared__ int cnt[256];
    __shared__ int ls[256];
    const int b = blockIdx.x;
    const int t = threadIdx.x;
    cnt[t] = 0;
    __syncthreads();
    const int beg = bucketOff[b], c = bucketCnt[b];
    for (int i = t; i < c; i += 256)
        atomicAdd(&cnt[binned[beg + i].y & 255], 1);
    __syncthreads();
    int v = cnt[t];
    ls[t] = v;
    __syncthreads();
    for (int off = 1; off < 256; off <<= 1) {
        int a = (t >= off) ? ls[t - off] : 0;
        __syncthreads();
        ls[t] += a;
        __syncthreads();
    }
    int node = b * 256 + t;
    if (node < N) offs[node] = beg + ls[t] - v;
    if (node == N - 1) offs[N] = ITEMS;
}

__global__ void csr_scatter_k(const int2* __restrict__ binned,
                              const int* __restrict__ bucketOff,
                              const int* __restrict__ bucketCnt,
                              const int* __restrict__ offs, int* __restrict__ csr) {
    __shared__ int fill[256];
    const int b = blockIdx.x;
    fill[threadIdx.x] = 0;
    __syncthreads();
    const int beg = bucketOff[b], c = bucketCnt[b];
    for (int i = threadIdx.x; i < c; i += 256) {
        int2 sd = binned[beg + i];
        int r = atomicAdd(&fill[sd.y & 255], 1);
        csr[offs[sd.y] + r] = sd.x;
    }
}

// ======= MFMA GEMM: Y[M,NCOL](f16) = X[M,128] @ W[128,NCOL] + fused alpha =======
// v_mfma_f32_16x16x32_f16, fragment layouts (dtype-independent, m89/m121):
//   A: lane l holds A[l&15][(l>>4)*8 + j];  B: lane l holds B[(l>>4)*8 + j][l&15]
//   D: lane l, reg j -> row (l>>4)*4+j, col l&15
// A/B staged to LDS in fragment-contiguous order -> lane-contiguous ds_read_b128.
// (cross-type LDS accesses here are safe: separated by __syncthreads, a full fence)

template<int NCOL, bool XF16>
__global__ __launch_bounds__(256) void gemm_alpha_mfma(
        const void* __restrict__ Xv, const float* __restrict__ W,
        const float* __restrict__ asrc, const float* __restrict__ adst,
        unsigned short* __restrict__ Y, float* __restrict__ As,
        float* __restrict__ Ad, int M) {
    constexpr int NT = NCOL / 16;            // 8 (layer1) or 4 (layer2)
    __shared__ alignas(16) short alds[4 * 4 * 64 * 8];      // [w][ks][lane][8]
    __shared__ alignas(16) short blds[NT * 4 * 64 * 8];     // [nt][ks][lane][8]

    const int t    = threadIdx.x;
    const int w    = t >> 6, lane = t & 63;
    const int row0 = blockIdx.x * 64;

    // ---- stage A tile (64 x 128) as f16 fragments ----
    if constexpr (!XF16) {
        const float* X = (const float*)Xv;
#pragma unroll
        for (int i = 0; i < 8; i++) {
            int flat = (i * 256 + t) * 4;
            int r = flat >> 7, k0 = flat & 127;
            int gr = row0 + r;
            float4 v = make_float4(0.f, 0.f, 0.f, 0.f);
            if (gr < M) v = *(const float4*)&X[(size_t)gr * 128 + k0];
            uint2 u = make_uint2(cvt2h(v.x, v.y), cvt2h(v.z, v.w));
            int frag = ((r >> 4) * 4 + (k0 >> 5)) * 64 + ((((k0 & 31) >> 3) << 4) | (r & 15));
            *(uint2*)&alds[frag * 8 + (k0 & 7)] = u;
        }
    } else {
        const unsigned short* X = (const unsigned short*)Xv;
#pragma unroll
        for (int i = 0; i < 4; i++) {
            int flat = (i * 256 + t) * 8;
            int r = flat >> 7, k0 = flat & 127;
            int gr = row0 + r;
            uint4 v = make_uint4(0u, 0u, 0u, 0u);
            if (gr < M) v = *(const uint4*)&X[(size_t)gr * 128 + k0];
            int frag = ((r >> 4) * 4 + (k0 >> 5)) * 64 + ((((k0 & 31) >> 3) << 4) | (r & 15));
            *(uint4*)&alds[frag * 8] = v;   // k0 % 8 == 0
        }
    }

    // ---- stage B (W: 128 x NCOL fp32) as f16 fragments ----
    {
        constexpr int KQ = 256 / NCOL;       // 2 or 4 k-quads covered per pass
        constexpr int BITER = 32 / KQ;       // 16 or 8 iterations
        int c = t % NCOL, kq = t / NCOL;
        int nt = c >> 4, n = c & 15;
#pragma unroll
        for (int i = 0; i < BITER; i++) {
            int k0 = (i * KQ + kq) * 4;
            uint2 u = make_uint2(
                cvt2h(W[(size_t)(k0 + 0) * NCOL + c], W[(size_t)(k0 + 1) * NCOL + c]),
                cvt2h(W[(size_t)(k0 + 2) * NCOL + c], W[(size_t)(k0 + 3) * NCOL + c]));
            int frag = (nt * 4 + (k0 >> 5)) * 64 + ((((k0 & 31) >> 3) << 4) | n);
            *(uint2*)&blds[frag * 8 + (k0 & 7)] = u;
        }
    }
    __syncthreads();

    // ---- MFMA: 16 rows x NCOL per wave ----
    f32x4 acc[NT];
#pragma unroll
    for (int nt = 0; nt < NT; nt++) acc[nt] = (f32x4){0.f, 0.f, 0.f, 0.f};
#pragma unroll
    for (int ks = 0; ks < 4; ks++) {
        half8v a = *(half8v*)&alds[((w * 4 + ks) * 64 + lane) * 8];
#pragma unroll
        for (int nt = 0; nt < NT; nt++) {
            half8v b = *(half8v*)&blds[((nt * 4 + ks) * 64 + lane) * 8];
            acc[nt] = __builtin_amdgcn_mfma_f32_16x16x32_f16(a, b, acc[nt], 0, 0, 0);
        }
    }

    // ---- epilogue: f16 store + alpha dots ----
    const int g = lane >> 4, col = lane & 15;
    float ps[4][4] = {}, pd[4][4] = {};      // [reg j][head]
#pragma unroll
    for (int nt = 0; nt < NT; nt++) {
        float av = asrc[nt * 16 + col];
        float dv = adst[nt * 16 + col];
        int h = (NCOL == 128) ? (nt >> 1) : nt;
#pragma unroll
        for (int j = 0; j < 4; j++) {
            float v = acc[nt][j];
            ps[j][h] = fmaf(v, av, ps[j][h]);
            pd[j][h] = fmaf(v, dv, pd[j][h]);
            int gr = row0 + w * 16 + 4 * g + j;
            if (gr < M) Y[(size_t)gr * NCOL + nt * 16 + col] = f2h(v);
        }
    }
#pragma unroll
    for (int m = 1; m < 16; m <<= 1) {
#pragma unroll
        for (int j = 0; j < 4; j++)
#pragma unroll
            for (int h = 0; h < 4; h++) {
                ps[j][h] += __shfl_xor(ps[j][h], m);
                pd[j][h] += __shfl_xor(pd[j][h], m);
            }
    }
    if (col == 0) {
#pragma unroll
        for (int j = 0; j < 4; j++) {
            int gr = row0 + w * 16 + 4 * g + j;
            if (gr < M) {
#pragma unroll
                for (int h = 0; h < 4; h++) {
                    As[gr * 4 + h] = ps[j][h];
                    Ad[gr * 4 + h] = pd[j][h];
                }
            }
        }
    }
}

// ------- aggregation: one wave per dst node ----------------------------------
// out[i] = ( sum_{e:dst=i} exp(leaky(As[src]+Ad[i])) * h[src] ) / sum exp(...)
// (segment-max dropped: softmax ratio invariant; weights < e^~5 -> f16-safe)
// R11: R7's register-only structure (2 edges/lane in flight, per-lane exp for
// its own head -- redundant across channel octets but VALU-parallel) + R10's
// verified f16 perm/fdot2 accumulate. No LDS weight table (R10: 4-way bank
// conflicts since bank ignored head), no fences.

template<bool RELU>
__global__ void agg128_k(const unsigned short* __restrict__ Hb,
                         const float* __restrict__ As, const float* __restrict__ Ad,
                         const int* __restrict__ offs, const int* __restrict__ csr,
                         const float* __restrict__ bias,
                         unsigned short* __restrict__ Outb, int n) {
    int wid  = (blockIdx.x * blockDim.x + threadIdx.x) >> 6;
    int lane = threadIdx.x & 63;
    if (wid >= n) return;
    const int g = lane >> 4;          // edge-slot group (0..3)
    const int q = lane & 15;          // channel octet
    const int head = q >> 2;
    const int beg = offs[wid], end = offs[wid + 1];
    const float ad = Ad[wid * 4 + head];
    float acc[8];
#pragma unroll
    for (int k = 0; k < 8; k++) acc[k] = 0.f;
    float sw = 0.f;

    for (int cb = beg; cb < end; cb += 64) {
        const int nc = min(64, end - cb);
        const int sreg = csr[cb + (lane < nc ? lane : 0)];   // 1 coalesced load
        const int ncr = (nc + 7) & ~7;
        for (int j = 0; j < ncr; j += 8) {
            const int e0 = j + g, e1 = j + g + 4;
            const bool v0 = e0 < nc, v1 = e1 < nc;
            const int s0 = __shfl(sreg, v0 ? e0 : 0);
            const int s1 = __shfl(sreg, v1 ? e1 : 0);
            const uint4 h0 = *(const uint4*)&Hb[(size_t)s0 * 128 + q * 8];
            const uint4 h1 = *(const uint4*)&Hb[(size_t)s1 * 128 + q * 8];
            float ev0 = As[s0 * 4 + head] + ad; ev0 = ev0 > 0.f ? ev0 : 0.2f * ev0;
            float ev1 = As[s1 * 4 + head] + ad; ev1 = ev1 > 0.f ? ev1 : 0.2f * ev1;
            const float w0 = v0 ? __expf(ev0) : 0.f;
            const float w1 = v1 ? __expf(ev1) : 0.f;
            sw += w0 + w1;
            const unsigned wp = cvt2h(w0, w1);   // (w_e0 lo, w_e1 hi)
#pragma unroll
            for (int k = 0; k < 4; k++) {
                unsigned d0 = (&h0.x)[k], d1 = (&h1.x)[k];
                acc[2 * k]     = fdot2b(wp, __builtin_amdgcn_perm(d1, d0, 0x05040100u), acc[2 * k]);
                acc[2 * k + 1] = fdot2b(wp, __builtin_amdgcn_perm(d1, d0, 0x07060302u), acc[2 * k + 1]);
            }
        }
    }

    sw += __shfl_xor(sw, 16); sw += __shfl_xor(sw, 32);
#pragma unroll
    for (int k = 0; k < 8; k++) {
        acc[k] += __shfl_xor(acc[k], 16);
        acc[k] += __shfl_xor(acc[k], 32);
    }
    if (g == 0) {
        const float inv = 1.f / sw;
        float o[8];
#pragma unroll
        for (int k = 0; k < 8; k++) {
            float v = fmaf(acc[k], inv, bias[q * 8 + k]);
            if (RELU) v = fmaxf(v, 0.f);
            o[k] = v;
        }
        uint4 ov = make_uint4(cvt2h(o[0], o[1]), cvt2h(o[2], o[3]),
                              cvt2h(o[4], o[5]), cvt2h(o[6], o[7]));
        *(uint4*)&Outb[(size_t)wid * 128 + q * 8] = ov;
    }
}

__global__ void agg64_k(const unsigned short* __restrict__ Hb,
                        const float* __restrict__ As, const float* __restrict__ Ad,
                        const int* __restrict__ offs, const int* __restrict__ csr,
                        const float* __restrict__ bias,
                        float* __restrict__ Out, int n) {
    int wid  = (blockIdx.x * blockDim.x + threadIdx.x) >> 6;
    int lane = threadIdx.x & 63;
    if (wid >= n) return;
    const int g = lane >> 3;          // edge-slot group (0..7)
    const int q = lane & 7;           // channel octet
    const int head = q >> 1;
    const int beg = offs[wid], end = offs[wid + 1];
    const float ad = Ad[wid * 4 + head];
    float acc[8];
#pragma unroll
    for (int k = 0; k < 8; k++) acc[k] = 0.f;
    float sw = 0.f;

    for (int cb = beg; cb < end; cb += 64) {
        const int nc = min(64, end - cb);
        const int sreg = csr[cb + (lane < nc ? lane : 0)];
        const int ncr = (nc + 15) & ~15;
        for (int j = 0; j < ncr; j += 16) {
            const int e0 = j + g, e1 = j + g + 8;
            const bool v0 = e0 < nc, v1 = e1 < nc;
            const int s0 = __shfl(sreg, v0 ? e0 : 0);
            const int s1 = __shfl(sreg, v1 ? e1 : 0);
            const uint4 h0 = *(const uint4*)&Hb[(size_t)s0 * 64 + q * 8];
            const uint4 h1 = *(const uint4*)&Hb[(size_t)s1 * 64 + q * 8];
            float ev0 = As[s0 * 4 + head] + ad; ev0 = ev0 > 0.f ? ev0 : 0.2f * ev0;
            float ev1 = As[s1 * 4 + head] + ad; ev1 = ev1 > 0.f ? ev1 : 0.2f * ev1;
            const float w0 = v0 ? __expf(ev0) : 0.f;
            const float w1 = v1 ? __expf(ev1) : 0.f;
            sw += w0 + w1;
            const unsigned wp = cvt2h(w0, w1);
#pragma unroll
            for (int k = 0; k < 4; k++) {
                unsigned d0 = (&h0.x)[k], d1 = (&h1.x)[k];
                acc[2 * k]     = fdot2b(wp, __builtin_amdgcn_perm(d1, d0, 0x05040100u), acc[2 * k]);
                acc[2 * k + 1] = fdot2b(wp, __builtin_amdgcn_perm(d1, d0, 0x07060302u), acc[2 * k + 1]);
            }
        }
    }

    sw += __shfl_xor(sw, 8); sw += __shfl_xor(sw, 16); sw += __shfl_xor(sw, 32);
#pragma unroll
    for (int k = 0; k < 8; k++) {
        acc[k] += __shfl_xor(acc[k], 8);
        acc[k] += __shfl_xor(acc[k], 16);
        acc[k] += __shfl_xor(acc[k], 32);
    }
    if (g == 0) {
        const float inv = 1.f / sw;
        float4 o0, o1;
        o0.x = fmaf(acc[0], inv, bias[q * 8 + 0]);
        o0.y = fmaf(acc[1], inv, bias[q * 8 + 1]);
        o0.z = fmaf(acc[2], inv, bias[q * 8 + 2]);
        o0.w = fmaf(acc[3], inv, bias[q * 8 + 3]);
        o1.x = fmaf(acc[4], inv, bias[q * 8 + 4]);
        o1.y = fmaf(acc[5], inv, bias[q * 8 + 5]);
        o1.z = fmaf(acc[6], inv, bias[q * 8 + 6]);
        o1.w = fmaf(acc[7], inv, bias[q * 8 + 7]);
        *(float4*)&Out[(size_t)wid * 64 + q * 8]     = o0;
        *(float4*)&Out[(size_t)wid * 64 + q * 8 + 4] = o1;
    }
}

// ---------------- global add pool + FC ----------------

__global__ void pool_k(const float* __restrict__ h2, float* __restrict__ g, int n) {
    __shared__ float ls[256];
    int c   = threadIdx.x & 63;
    int rg  = (blockIdx.x * blockDim.x + threadIdx.x) >> 6;
    int nrg = (gridDim.x * blockDim.x) >> 6;
    float acc = 0.f;
    for (int r = rg; r < n; r += nrg) acc += h2[(size_t)r * 64 + c];
    ls[threadIdx.x] = acc;
    __syncthreads();
    if (threadIdx.x < 64) {
        float v = ls[threadIdx.x] + ls[threadIdx.x + 64] +
                  ls[threadIdx.x + 128] + ls[threadIdx.x + 192];
        atomicAdd(&g[c], v);
    }
}

__global__ void fc_k(const float* __restrict__ g, const float* __restrict__ w,
                     const float* __restrict__ b, float* __restrict__ out) {
    int j = threadIdx.x;
    if (j < 2) {
        float acc = b[j];
        for (int c = 0; c < 64; c++) acc = fmaf(g[c], w[c * 2 + j], acc);
        out[j] = acc;
    }
}

// ---------------- launch ----------------

static inline size_t align256(size_t x) { return (x + 255) & ~(size_t)255; }

extern "C" void kernel_launch(void* const* d_in, const int* in_sizes, int n_in,
                              void* d_out, int out_size, void* d_ws, size_t ws_size,
                              hipStream_t stream) {
    const float* x     = (const float*)d_in[0];
    const int*   ei    = (const int*)  d_in[1];
    const float* W1    = (const float*)d_in[2];
    const float* asrc1 = (const float*)d_in[3];
    const float* adst1 = (const float*)d_in[4];
    const float* b1    = (const float*)d_in[5];
    const float* W2    = (const float*)d_in[6];
    const float* asrc2 = (const float*)d_in[7];
    const float* adst2 = (const float*)d_in[8];
    const float* b2    = (const float*)d_in[9];
    const float* fcw   = (const float*)d_in[10];
    const float* fcb   = (const float*)d_in[11];
    float* out = (float*)d_out;

    const int N = in_sizes[0] / 128;
    const int E = in_sizes[1] / 2;
    const int ITEMS = E + N;
    const int NB = (N + 255) >> 8;

    // workspace carve-up
    char* w = (char*)d_ws;
    size_t off = 0;
    int* offs  = (int*)(w + off); off = align256(off + (size_t)(N + 1) * 4);
    int* bCnt  = (int*)(w + off); off = align256(off + 512 * 4);
    int* bOff  = (int*)(w + off); off = align256(off + 512 * 4);
    int* bFill = (int*)(w + off); off = align256(off + 512 * 4);
    int* csr   = (int*)(w + off); off = align256(off + (size_t)ITEMS * 4);
    int2* binned = (int2*)(w + off); off = align256(off + (size_t)ITEMS * 8);
    float* As = (float*)(w + off); off = align256(off + (size_t)N * 4 * 4);
    float* Ad = (float*)(w + off); off = align256(off + (size_t)N * 4 * 4);
    float* g  = (float*)(w + off); off = align256(off + 66 * 4);
    unsigned short* bufH = (unsigned short*)(w + off); off = align256(off + (size_t)N * 128 * 2);
    unsigned short* bufO = (unsigned short*)(w + off); off = align256(off + (size_t)N * 128 * 4);
    float* out2 = (float*)bufO;   // layer-2 output aliases bufO (fp32, N x 64)

    // --- build CSR (by dst, self loops included) ---
    init_k<<<1, 512, 0, stream>>>(bCnt, g);
    bucket_hist_k<<<1024, 256, 0, stream>>>(ei, bCnt, E, N, NB);
    bucket_scan_k<<<1, 512, 0, stream>>>(bCnt, bOff, bFill, NB);
    bin_scatter_k<<<(ITEMS + 4095) / 4096, 256, 0, stream>>>(ei, bFill, binned, E, N);
    node_offs_k<<<NB, 256, 0, stream>>>(binned, bOff, bCnt, offs, N, ITEMS);
    csr_scatter_k<<<NB, 256, 0, stream>>>(binned, bOff, bCnt, offs, csr);

    // --- layer 1 ---
    gemm_alpha_mfma<128, false><<<(N + 63) / 64, 256, 0, stream>>>(
        x, W1, asrc1, adst1, bufH, As, Ad, N);
    agg128_k<true><<<(N * 64 + 255) / 256, 256, 0, stream>>>(
        bufH, As, Ad, offs, csr, b1, bufO, N);

    // --- layer 2 ---
    gemm_alpha_mfma<64, true><<<(N + 63) / 64, 256, 0, stream>>>(
        bufO, W2, asrc2, adst2, bufH, As, Ad, N);
    agg64_k<<<(N * 64 + 255) / 256, 256, 0, stream>>>(
        bufH, As, Ad, offs, csr, b2, out2, N);

    // --- pool + fc ---
    pool_k<<<256, 256, 0, stream>>>(out2, g, N);
    fc_k<<<1, 64, 0, stream>>>(g, fcw, fcb, out);
}